// Round 1
// baseline (278.702 us; speedup 1.0000x reference)
//
#include <hip/hip_runtime.h>

#define KS    11
#define HH    512
#define WW    512
#define OUTD  502          // HH - KS + 1
#define OH    34           // output rows per band
#define ROWS  44           // OH + KS - 1 rows staged per band (4 groups of 11)
#define NB    15           // ceil(502/34)
#define NIMG  96           // N*C = 32*3
#define PADW  524          // 512 + pad for horizontal reads up to c+11

// Streaming separable SSIM:
//  - block = (image, 44-row band); 256 threads x 2 cols = 512 cols
//  - per row: stage x,y row in double-buffered LDS (1 barrier/row),
//    horizontal 11-tap conv of {x,y,x2,y2,xy} per thread (2 cols),
//    vertical conv via 11 rotating register accumulators per (quantity,col)
//    -> each horizontal result consumed exactly once, no LDS for vertical pass.
__global__ __launch_bounds__(256, 2)
void ssim_main(const float* __restrict__ xg, const float* __restrict__ yg,
               const float* __restrict__ win, double* __restrict__ acc_out)
{
    __shared__ float xs[2][PADW];
    __shared__ float ys[2][PADW];
    __shared__ float wsums[4];

    const int tid  = threadIdx.x;
    const int img  = blockIdx.x % NIMG;
    const int band = blockIdx.x / NIMG;
    const int row0 = band * OH;
    const int c0   = 2 * tid;

    // Recover 1D gaussian from the (normalized, rank-1) 2D window: row sums.
    float g[KS];
    #pragma unroll
    for (int i = 0; i < KS; i++) {
        float s = 0.f;
        #pragma unroll
        for (int j = 0; j < KS; j++) s += win[i * KS + j];
        g[i] = s;
    }

    // Zero the LDS pad (cols 512..PADW-1); only feeds invalid outputs but must be finite.
    if (tid < (PADW - WW)) {
        xs[0][WW + tid] = 0.f; xs[1][WW + tid] = 0.f;
        ys[0][WW + tid] = 0.f; ys[1][WW + tid] = 0.f;
    }

    const float* xi = xg + (size_t)img * HH * WW;
    const float* yi = yg + (size_t)img * HH * WW;

    // rotating vertical accumulators [quantity][col][slot]
    float acc[5][2][KS];
    #pragma unroll
    for (int q = 0; q < 5; q++)
        #pragma unroll
        for (int c = 0; c < 2; c++)
            #pragma unroll
            for (int s = 0; s < KS; s++) acc[q][c][s] = 0.f;

    float ssum = 0.f;

    const float C1 = 0.0001f;  // (0.01)^2
    const float C2 = 0.0009f;  // (0.03)^2

    // prologue: row 0 -> buf0, prefetch row 1 into regs
    float2 vx, vy;
    {
        int gr = row0; if (gr > HH - 1) gr = HH - 1;
        vx = *(const float2*)&xi[(size_t)gr * WW + c0];
        vy = *(const float2*)&yi[(size_t)gr * WW + c0];
        xs[0][c0] = vx.x; xs[0][c0 + 1] = vx.y;
        ys[0][c0] = vy.x; ys[0][c0 + 1] = vy.y;
        gr = row0 + 1; if (gr > HH - 1) gr = HH - 1;
        vx = *(const float2*)&xi[(size_t)gr * WW + c0];
        vy = *(const float2*)&yi[(size_t)gr * WW + c0];
    }
    __syncthreads();

    #pragma unroll 1
    for (int rb = 0; rb < ROWS / KS; rb++) {
        #pragma unroll
        for (int rr = 0; rr < KS; rr++) {
            const int r = rb * KS + rr;

            // ---- read 12 x / 12 y for this row from LDS (b64, contiguous) ----
            const float* xb = xs[r & 1];
            const float* yb = ys[r & 1];
            float xv[12], yv[12];
            #pragma unroll
            for (int k = 0; k < 6; k++) {
                float2 a = *(const float2*)&xb[c0 + 2 * k];
                float2 b = *(const float2*)&yb[c0 + 2 * k];
                xv[2 * k] = a.x; xv[2 * k + 1] = a.y;
                yv[2 * k] = b.x; yv[2 * k + 1] = b.y;
            }

            // ---- write prefetched row r+1 into the other buffer; prefetch r+2 ----
            if (r + 1 < ROWS) {
                float* xw = xs[(r + 1) & 1];
                float* yw = ys[(r + 1) & 1];
                xw[c0] = vx.x; xw[c0 + 1] = vx.y;
                yw[c0] = vy.x; yw[c0 + 1] = vy.y;
            }
            if (r + 2 < ROWS) {
                int gr = row0 + r + 2; if (gr > HH - 1) gr = HH - 1;
                vx = *(const float2*)&xi[(size_t)gr * WW + c0];
                vy = *(const float2*)&yi[(size_t)gr * WW + c0];
            }

            // ---- products once, shared by both columns ----
            float xx[12], yy[12], xy[12];
            #pragma unroll
            for (int k = 0; k < 12; k++) {
                xx[k] = xv[k] * xv[k];
                yy[k] = yv[k] * yv[k];
                xy[k] = xv[k] * yv[k];
            }

            // ---- horizontal 11-tap conv for 2 cols x 5 quantities ----
            float h[5][2];
            #pragma unroll
            for (int q = 0; q < 5; q++) { h[q][0] = 0.f; h[q][1] = 0.f; }
            #pragma unroll
            for (int j = 0; j < KS; j++) {
                const float gj = g[j];
                h[0][0] = fmaf(gj, xv[j], h[0][0]); h[0][1] = fmaf(gj, xv[j + 1], h[0][1]);
                h[1][0] = fmaf(gj, yv[j], h[1][0]); h[1][1] = fmaf(gj, yv[j + 1], h[1][1]);
                h[2][0] = fmaf(gj, xx[j], h[2][0]); h[2][1] = fmaf(gj, xx[j + 1], h[2][1]);
                h[3][0] = fmaf(gj, yy[j], h[3][0]); h[3][1] = fmaf(gj, yy[j + 1], h[3][1]);
                h[4][0] = fmaf(gj, xy[j], h[4][0]); h[4][1] = fmaf(gj, xy[j + 1], h[4][1]);
            }

            // ---- vertical accumulate into rotating slots (slot is compile-time) ----
            #pragma unroll
            for (int i = 0; i < KS; i++) {
                const int slot = (rr - i + KS) % KS;
                const float gi = g[i];
                #pragma unroll
                for (int q = 0; q < 5; q++) {
                    acc[q][0][slot] = fmaf(gi, h[q][0], acc[q][0][slot]);
                    acc[q][1][slot] = fmaf(gi, h[q][1], acc[q][1][slot]);
                }
            }

            // ---- emit completed output row jloc = r-10 (slot (rr+1)%11) ----
            const int es   = (rr + 1) % KS;
            const int jloc = r - (KS - 1);
            if (jloc >= 0 && (row0 + jloc) < OUTD) {
                #pragma unroll
                for (int c = 0; c < 2; c++) {
                    if (c0 + c < OUTD) {
                        const float mx  = acc[0][c][es], my  = acc[1][c][es];
                        const float Sxx = acc[2][c][es], Syy = acc[3][c][es], Sxy = acc[4][c][es];
                        const float mxx = mx * mx, myy = my * my, mxy = mx * my;
                        const float sxx = Sxx - mxx, syy = Syy - myy, sxy = Sxy - mxy;
                        const float num = (2.f * mxy + C1) * (2.f * sxy + C2);
                        const float den = (mxx + myy + C1) * (sxx + syy + C2);
                        float rc = __builtin_amdgcn_rcpf(den);
                        rc = rc * fmaf(-den, rc, 2.0f);   // one NR step: ~0.5 ulp
                        ssum = fmaf(num, rc, ssum);
                    }
                }
            }
            // reset emitted slots for reuse (must happen every row, valid or not)
            #pragma unroll
            for (int q = 0; q < 5; q++) { acc[q][0][es] = 0.f; acc[q][1][es] = 0.f; }

            __syncthreads();
        }
    }

    // block reduction: wave shuffle then cross-wave via LDS
    #pragma unroll
    for (int off = 32; off > 0; off >>= 1)
        ssum += __shfl_down(ssum, off);
    const int wave = tid >> 6;
    if ((tid & 63) == 0) wsums[wave] = ssum;
    __syncthreads();
    if (tid == 0) {
        float s = wsums[0] + wsums[1] + wsums[2] + wsums[3];
        atomicAdd(acc_out, (double)s);
    }
}

__global__ void ssim_finalize(const double* __restrict__ acc, float* __restrict__ out)
{
    // total outputs: 96 * 502 * 502 = 24,192,384
    out[0] = (float)(acc[0] * (1.0 / 24192384.0));
}

extern "C" void kernel_launch(void* const* d_in, const int* in_sizes, int n_in,
                              void* d_out, int out_size, void* d_ws, size_t ws_size,
                              hipStream_t stream)
{
    const float* x   = (const float*)d_in[0];
    const float* y   = (const float*)d_in[1];
    const float* win = (const float*)d_in[2];
    float* out = (float*)d_out;
    double* acc = (double*)d_ws;

    hipMemsetAsync(acc, 0, sizeof(double), stream);
    ssim_main<<<dim3(NIMG * NB), dim3(256), 0, stream>>>(x, y, win, acc);
    ssim_finalize<<<dim3(1), dim3(1), 0, stream>>>(acc, out);
}